// Round 5
// baseline (166.443 us; speedup 1.0000x reference)
//
#include <hip/hip_runtime.h>
#include <hip/hip_bf16.h>

#define Hd 64
#define Sd 128
#define Bd 64
#define Nn 8192
#define EPSd 1e-5f

__device__ __forceinline__ float wred_sum(float v) {
    for (int m = 32; m; m >>= 1) v += __shfl_xor(v, m);
    return v;
}
__device__ __forceinline__ float wred_max(float v) {
    for (int m = 32; m; m >>= 1) v = fmaxf(v, __shfl_xor(v, m));
    return v;
}
// 64-lane inclusive scan
__device__ __forceinline__ float wscan_incl(float x, int lane) {
    #pragma unroll
    for (int d = 1; d < 64; d <<= 1) {
        float t = __shfl_up(x, d);
        if (lane >= d) x += t;
    }
    return x;
}

// A: conv1+bn1+relu -> conv2+bn2+relu -> (LDS) -> Wh, s1, s2  (16 nodes/block, 512 blocks)
__global__ __launch_bounds__(256) void kA_feat_wh(
        const float* __restrict__ x,
        const float* __restrict__ c1w, const float* __restrict__ c1b,
        const float* __restrict__ b1g, const float* __restrict__ b1b,
        const float* __restrict__ b1m, const float* __restrict__ b1v,
        const float* __restrict__ c2w, const float* __restrict__ c2b,
        const float* __restrict__ b2g, const float* __restrict__ b2b,
        const float* __restrict__ b2m, const float* __restrict__ b2v,
        const float* __restrict__ gW, const float* __restrict__ gWb,
        const float* __restrict__ a1, const float* __restrict__ a2,
        float* __restrict__ Wh, float* __restrict__ s1, float* __restrict__ s2) {
    __shared__ float buf[13440];        // phase1: h1[0..1152) | wtk[1152..13440)
    float* h1  = buf;                   // [col][cin], 18*64
    float* wtk = buf + 1152;            // [(k*16+cin4)*256 + c*4 + j]
    int b  = blockIdx.x >> 3;
    int s0 = (blockIdx.x & 7) * 16;
    int tid = threadIdx.x;
    for (int idx = tid; idx < 12288; idx += 256) {
        int j    = idx & 3;
        int c    = (idx >> 2) & 63;
        int cin4 = (idx >> 8) & 15;
        int k    = idx >> 12;
        wtk[idx] = c2w[(c * 64 + cin4 * 4 + j) * 3 + k];
    }
    for (int idx = tid; idx < 1152; idx += 256) {
        int cin = idx & 63;
        int col = idx >> 6;
        int s   = s0 - 1 + col;
        float v = 0.f;
        if (s >= 0 && s < Sd) {
            float xm = (s > 0)      ? x[b * Sd + s - 1] : 0.f;
            float x0 = x[b * Sd + s];
            float xp = (s < Sd - 1) ? x[b * Sd + s + 1] : 0.f;
            float y  = c1w[cin * 3 + 0] * xm + c1w[cin * 3 + 1] * x0 + c1w[cin * 3 + 2] * xp + c1b[cin];
            float inv = b1g[cin] * rsqrtf(b1v[cin] + EPSd);
            v = fmaxf(y * inv + (b1b[cin] - b1m[cin] * inv), 0.f);
        }
        h1[col * 64 + cin] = v;
    }
    __syncthreads();
    int c = tid & 63, g = tid >> 6;     // 4 positions per thread: sl = g*4+p
    float inv2 = b2g[c] * rsqrtf(b2v[c] + EPSd);
    float sh2  = b2b[c] - b2m[c] * inv2;
    float acc[4];
    #pragma unroll
    for (int p = 0; p < 4; ++p) acc[p] = c2b[c];
    {
        const float4* h14 = (const float4*)h1;
        const float4* wt4 = (const float4*)wtk;
        for (int cin4 = 0; cin4 < 16; ++cin4) {
            float4 xs[6];
            #pragma unroll
            for (int q = 0; q < 6; ++q) xs[q] = h14[(g * 4 + q) * 16 + cin4];
            #pragma unroll
            for (int k = 0; k < 3; ++k) {
                float4 w4 = wt4[(k * 16 + cin4) * 64 + c];
                #pragma unroll
                for (int p = 0; p < 4; ++p) {
                    float4 x4 = xs[p + k];
                    acc[p] += w4.x * x4.x + w4.y * x4.y + w4.z * x4.z + w4.w * x4.w;
                }
            }
        }
    }
    __syncthreads();   // conv reads done; safe to overwrite
    float*  xfl  = buf;                    // [sl][c], 16*64
    float4* gWT4 = (float4*)(buf + 1152);  // [kk4*64 + h]
    #pragma unroll
    for (int p = 0; p < 4; ++p)
        xfl[(g * 4 + p) * 64 + c] = fmaxf(acc[p] * inv2 + sh2, 0.f);
    for (int fidx = tid; fidx < 1024; fidx += 256) {
        int h_ = fidx >> 4, kk4 = fidx & 15;
        gWT4[kk4 * 64 + h_] = ((const float4*)gW)[fidx];
    }
    __syncthreads();
    int h = tid & 63, w = tid >> 6;
    float4 wreg[16];
    #pragma unroll
    for (int kk4 = 0; kk4 < 16; ++kk4) wreg[kk4] = gWT4[kk4 * 64 + h];
    float va1 = a1[h], va2 = a2[h], bias = gWb[h];
    const float4* xf4 = (const float4*)xfl;
    int n0 = b * Sd + s0;
    for (int q = 0; q < 4; ++q) {
        int sl = w * 4 + q;
        float accw = bias;
        #pragma unroll
        for (int kk4 = 0; kk4 < 16; ++kk4) {
            float4 x4 = xf4[sl * 16 + kk4];
            accw += wreg[kk4].x * x4.x + wreg[kk4].y * x4.y + wreg[kk4].z * x4.z + wreg[kk4].w * x4.w;
        }
        int n = n0 + sl;
        Wh[n * 64 + h] = accw;
        float r1 = wred_sum(accw * va1);
        float r2 = wred_sum(accw * va2);
        if (h == 0) { s1[n] = r1; s2[n] = r2; }
    }
}

// B: partial ranks AND partial k-counts + per-part max; block 0 zeroes flags
__global__ __launch_bounds__(256) void kB_rank(
        const float* __restrict__ s2, const float* __restrict__ s1,
        const float* __restrict__ gab,
        int* __restrict__ rankPart, int* __restrict__ kPart,
        float* __restrict__ pmax, int* __restrict__ flagsZ) {
    __shared__ float4 ts4[64];
    int bid = blockIdx.x;
    int jg = bid >> 5, part = bid & 31;
    int tid = threadIdx.x;
    if (bid == 0) {
        for (int i = tid; i < 640; i += 256) flagsZ[i] = 0;
    }
    if (tid < 64) ts4[tid] = ((const float4*)(s2 + part * 256))[tid];
    __syncthreads();
    if (jg == 0 && tid < 64) {
        float4 t4 = ts4[tid];
        float m = fmaxf(fmaxf(t4.x, t4.y), fmaxf(t4.z, t4.w));
        m = wred_max(m);
        if (tid == 0) pmax[part] = m;
    }
    int j = jg * 256 + tid;
    float tj = s2[j];
    float negc = -(s1[j] + gab[0]);
    int jloc = j - part * 256;
    int cntR = 0, cntK = 0;
    #pragma unroll 4
    for (int q = 0; q < 64; ++q) {
        float4 t4 = ts4[q];
        int rb = q * 4;
        cntR += (t4.x < tj || (t4.x == tj && rb     < jloc)) ? 1 : 0;
        cntR += (t4.y < tj || (t4.y == tj && rb + 1 < jloc)) ? 1 : 0;
        cntR += (t4.z < tj || (t4.z == tj && rb + 2 < jloc)) ? 1 : 0;
        cntR += (t4.w < tj || (t4.w == tj && rb + 3 < jloc)) ? 1 : 0;
        cntK += (t4.x <= negc) ? 1 : 0;
        cntK += (t4.y <= negc) ? 1 : 0;
        cntK += (t4.z <= negc) ? 1 : 0;
        cntK += (t4.w <= negc) ? 1 : 0;
    }
    rankPart[part * 8192 + j] = cntR;
    kPart[part * 8192 + j]    = cntK;
}

// CDE: scatter + chunk sums + prefix expand, one 64-block kernel, 2 flag barriers
__global__ __launch_bounds__(256) void kCDE(
        const float* __restrict__ Wh, const float* __restrict__ s2,
        const int* __restrict__ rankPart, const int* __restrict__ kPart,
        float* __restrict__ Rpos, float* __restrict__ Rneg,
        float* __restrict__ spos, float* __restrict__ sneg,
        int* __restrict__ kk,
        float* __restrict__ csP, float* __restrict__ csN,
        float* __restrict__ csp, float* __restrict__ csn,
        float* __restrict__ Ppos, float* __restrict__ Pneg,
        float* __restrict__ ppos, float* __restrict__ pneg,
        int* __restrict__ flag1, int* __restrict__ flag2) {
    __shared__ int rsl[4096], ksl[4096];
    __shared__ float e1s[128], e2s[128];
    __shared__ int rj[128];
    __shared__ float ldsA[4][64], ldsB[4][64], cbPs[64], cbNs[64];
    int ch = blockIdx.x, tid = threadIdx.x;
    int j0 = ch * 128;
    // ---- phase C: sum partials, scatter into rank order ----
    for (int idx = tid; idx < 4096; idx += 256) {
        int p = idx >> 7, jj = idx & 127;
        rsl[idx] = rankPart[p * 8192 + j0 + jj];
        ksl[idx] = kPart[p * 8192 + j0 + jj];
    }
    __syncthreads();
    if (tid < 128) {
        int r = 0, kq = 0;
        #pragma unroll
        for (int p = 0; p < 32; ++p) { r += rsl[p * 128 + tid]; kq += ksl[p * 128 + tid]; }
        rj[tid] = r;
        float t = s2[j0 + tid];
        float e1 = expf(t), e2 = expf(0.2f * t);
        e1s[tid] = e1; e2s[tid] = e2;
        spos[r] = e1; sneg[r] = e2;
        kk[j0 + tid] = kq;
    }
    __syncthreads();
    for (int it = tid; it < 2048; it += 256) {
        int jj = it >> 4, h4 = it & 15;
        int r = rj[jj];
        float4 wv = ((const float4*)Wh)[(j0 + jj) * 16 + h4];
        float e1 = e1s[jj], e2 = e2s[jj];
        ((float4*)Rpos)[r * 16 + h4] = make_float4(e1 * wv.x, e1 * wv.y, e1 * wv.z, e1 * wv.w);
        ((float4*)Rneg)[r * 16 + h4] = make_float4(e2 * wv.x, e2 * wv.y, e2 * wv.z, e2 * wv.w);
    }
    __threadfence();
    __syncthreads();
    if (tid == 0) atomicExch(&flag1[ch], 1);
    if (tid < 64) { while (atomicAdd(&flag1[tid], 0) == 0) __builtin_amdgcn_s_sleep(2); }
    __syncthreads();
    __threadfence();
    // ---- phase D: chunk sums (rows kept in registers) ----
    int h = tid & 63, w = tid >> 6;
    int rb = ch * 128 + w * 32;
    float v[32], u[32];
    #pragma unroll
    for (int r = 0; r < 32; ++r) { v[r] = Rpos[(rb + r) * 64 + h]; u[r] = Rneg[(rb + r) * 64 + h]; }
    double sP = 0.0, sN = 0.0;
    #pragma unroll
    for (int r = 0; r < 32; ++r) { sP += v[r]; sN += u[r]; }
    float sPf = (float)sP, sNf = (float)sN;
    ldsA[w][h] = sPf; ldsB[w][h] = sNf;
    __syncthreads();
    if (w == 0) {
        csP[ch * 64 + h] = ldsA[0][h] + ldsA[1][h] + ldsA[2][h] + ldsA[3][h];
    } else if (w == 1) {
        csN[ch * 64 + h] = ldsB[0][h] + ldsB[1][h] + ldsB[2][h] + ldsB[3][h];
    } else if (w == 2) {
        float vv = spos[ch * 128 + h] + spos[ch * 128 + 64 + h];
        vv = wred_sum(vv);
        if (h == 0) csp[ch] = vv;
    } else {
        float vv = sneg[ch * 128 + h] + sneg[ch * 128 + 64 + h];
        vv = wred_sum(vv);
        if (h == 0) csn[ch] = vv;
    }
    __threadfence();
    __syncthreads();
    if (tid == 0) atomicExch(&flag2[ch], 1);
    if (tid < 64) { while (atomicAdd(&flag2[tid], 0) == 0) __builtin_amdgcn_s_sleep(2); }
    __syncthreads();
    __threadfence();
    // ---- phase E: bases + prefix writes ----
    double bp = 0.0, bn = 0.0;
    for (int p = w; p < ch; p += 4) { bp += csP[p * 64 + h]; bn += csN[p * 64 + h]; }
    ldsA[w][h] = (float)bp; ldsB[w][h] = (float)bn;
    __syncthreads();
    if (w == 0) {
        cbPs[h] = ldsA[0][h] + ldsA[1][h] + ldsA[2][h] + ldsA[3][h];
        cbNs[h] = ldsB[0][h] + ldsB[1][h] + ldsB[2][h] + ldsB[3][h];
    }
    __syncthreads();
    ldsA[w][h] = sPf; ldsB[w][h] = sNf;
    __syncthreads();
    float offP = cbPs[h], offN = cbNs[h];
    #pragma unroll
    for (int w2 = 0; w2 < 4; ++w2) if (w2 < w) { offP += ldsA[w2][h]; offN += ldsB[w2][h]; }
    double a = 0.0;
    #pragma unroll
    for (int r = 0; r < 32; ++r) { Ppos[(rb + r) * 64 + h] = offP + (float)a; a += v[r]; }
    if (ch == 63 && w == 3) Ppos[Nn * 64 + h] = offP + (float)a;
    a = 0.0;
    #pragma unroll
    for (int r = 0; r < 32; ++r) { Pneg[(rb + r) * 64 + h] = offN + (float)a; a += u[r]; }
    if (ch == 63 && w == 3) Pneg[Nn * 64 + h] = offN + (float)a;
    // scalar prefixes
    if (w == 0) {
        int lane = h;
        float bs = (lane < ch) ? csp[lane] : 0.f;
        bs = wred_sum(bs);
        float v0 = spos[ch * 128 + lane], v1 = spos[ch * 128 + 64 + lane];
        float i0 = wscan_incl(v0, lane);
        float t0 = __shfl(i0, 63);
        float i1 = wscan_incl(v1, lane);
        ppos[ch * 128 + lane]      = bs + i0 - v0;
        ppos[ch * 128 + 64 + lane] = bs + t0 + i1 - v1;
        if (ch == 63 && lane == 63) ppos[Nn] = bs + t0 + i1;
    } else if (w == 1) {
        int lane = h;
        float bs = (lane < ch) ? csn[lane] : 0.f;
        bs = wred_sum(bs);
        float v0 = sneg[ch * 128 + lane], v1 = sneg[ch * 128 + 64 + lane];
        float i0 = wscan_incl(v0, lane);
        float t0 = __shfl(i0, 63);
        float i1 = wscan_incl(v1, lane);
        pneg[ch * 128 + lane]      = bs + i0 - v0;
        pneg[ch * 128 + 64 + lane] = bs + t0 + i1 - v1;
        if (ch == 63 && lane == 63) pneg[Nn] = bs + t0 + i1;
    }
}

// FG: per-node hp + time-attn -> h2; then blocks bid%8==0 pool+MLP their batch
__global__ __launch_bounds__(256) void kFG(
        const float* __restrict__ s1, const int* __restrict__ kk,
        const float* __restrict__ pmax, const float* __restrict__ gab,
        const float* __restrict__ Ppos, const float* __restrict__ Pneg,
        const float* __restrict__ ppos, const float* __restrict__ pneg,
        const float* __restrict__ taW, const float* __restrict__ tab,
        const float* __restrict__ p1W, const float* __restrict__ p1b,
        const float* __restrict__ p2W, const float* __restrict__ p2b,
        float* __restrict__ h2, float* __restrict__ out,
        int* __restrict__ flagF) {
    __shared__ float4 wt4[1024];   // taW: [kk4*64 + h]
    __shared__ float hl[16 * 64];
    __shared__ float pacc[4 * 64];
    __shared__ float pl[64];
    __shared__ float p1s[32 * 65];
    int tid = threadIdx.x, bid = blockIdx.x;
    // ---- phase F ----
    for (int fidx = tid; fidx < 1024; fidx += 256) {
        int h_ = fidx >> 4, kk4 = fidx & 15;
        wt4[kk4 * 64 + h_] = ((const float4*)taW)[fidx];
    }
    float tmx = pmax[tid & 31];
    tmx = wred_max(tmx);
    __syncthreads();
    int h = tid & 63, w = tid >> 6;
    float gabv = gab[0];
    float tabv = tab[h];
    float Tp  = Ppos[Nn * 64 + h];
    float ppT = ppos[Nn];
    for (int r = 0; r < 4; ++r) {
        int n = bid * 16 + w * 4 + r;
        float c = s1[n] + gabv;
        int k = kk[n];
        float z = c + tmx;
        float m = (z >= 0.f) ? z : 0.2f * z;
        float E1 = expf(c - m), E2 = expf(0.2f * c - m);
        float Pp = Ppos[k * 64 + h], Pn = Pneg[k * 64 + h];
        float num = E1 * (Tp - Pp) + E2 * Pn;
        float den = E1 * (ppT - ppos[k]) + E2 * pneg[k];
        float hp = num / den;
        int slot = w * 4 + r;
        hl[slot * 64 + h] = hp;
        float vv = tabv;
        const float4* hlr = (const float4*)&hl[slot * 64];
        #pragma unroll
        for (int kk4 = 0; kk4 < 16; ++kk4) {
            float4 w4 = wt4[kk4 * 64 + h];
            float4 x4 = hlr[kk4];
            vv += w4.x * x4.x + w4.y * x4.y + w4.z * x4.z + w4.w * x4.w;
        }
        float mx = wred_max(vv);
        float e = expf(vv - mx);
        float se = wred_sum(e);
        h2[n * 64 + h] = hp * (e / se);
    }
    __threadfence();
    __syncthreads();
    if (tid == 0) atomicExch(&flagF[bid], 1);
    if (bid & 7) return;
    // ---- phase G (one block per batch) ----
    int b = bid >> 3;
    if (tid < 8) { while (atomicAdd(&flagF[bid + tid], 0) == 0) __builtin_amdgcn_s_sleep(2); }
    __syncthreads();
    __threadfence();
    for (int idx = tid; idx < 2048; idx += 256) {
        int q = idx >> 6, kq = idx & 63;
        p1s[q * 65 + kq] = p1W[idx];
    }
    float a = 0.f;
    for (int s = w * 32; s < w * 32 + 32; ++s) a += h2[(b * Sd + s) * 64 + h];
    pacc[w * 64 + h] = a;
    __syncthreads();
    if (w == 0) {
        float pooled = (pacc[h] + pacc[64 + h] + pacc[128 + h] + pacc[192 + h]) * (1.f / 128.f);
        pl[h] = pooled;
        float val = 0.f;
        if (h < 32) {
            float acc = p1b[h];
            #pragma unroll
            for (int kq = 0; kq < 64; ++kq) acc += p1s[h * 65 + kq] * pl[kq];
            val = p2W[h] * fmaxf(acc, 0.f);
        }
        val = wred_sum(val);
        if (h == 0) out[b] = val + p2b[0];
    }
}

extern "C" void kernel_launch(void* const* d_in, const int* in_sizes, int n_in,
                              void* d_out, int out_size, void* d_ws, size_t ws_size,
                              hipStream_t stream) {
    const float* x    = (const float*)d_in[0];
    const float* c1w  = (const float*)d_in[1];
    const float* c1b  = (const float*)d_in[2];
    const float* b1g  = (const float*)d_in[3];
    const float* b1b  = (const float*)d_in[4];
    const float* b1m  = (const float*)d_in[5];
    const float* b1v  = (const float*)d_in[6];
    const float* c2w  = (const float*)d_in[7];
    const float* c2b  = (const float*)d_in[8];
    const float* b2g  = (const float*)d_in[9];
    const float* b2b  = (const float*)d_in[10];
    const float* b2m  = (const float*)d_in[11];
    const float* b2v  = (const float*)d_in[12];
    const float* gW   = (const float*)d_in[13];
    const float* gWb  = (const float*)d_in[14];
    const float* ga1  = (const float*)d_in[15];
    const float* ga2  = (const float*)d_in[16];
    const float* gab  = (const float*)d_in[17];
    const float* taW  = (const float*)d_in[18];
    const float* tab  = (const float*)d_in[19];
    const float* p1W  = (const float*)d_in[20];
    const float* p1b  = (const float*)d_in[21];
    const float* p2W  = (const float*)d_in[22];
    const float* p2b  = (const float*)d_in[23];
    float* out = (float*)d_out;

    float* ws = (float*)d_ws;
    float* Wh      = ws;                    // 524288
    float* s1      = Wh + 524288;           // 8192
    float* s2v     = s1 + 8192;             // 8192
    float* spos    = s2v + 8192;            // 8192
    float* sneg    = spos + 8192;           // 8192
    float* ppos    = sneg + 8192;           // 8256 (8193 used)
    float* pneg    = ppos + 8256;           // 8256
    float* csP     = pneg + 8256;           // 4096
    float* csN     = csP + 4096;            // 4096
    float* csp     = csN + 4096;            // 64
    float* csn     = csp + 64;              // 64
    float* pmax    = csn + 64;              // 64 (32 used)
    int*   flags   = (int*)(pmax + 64);     // 640: flag1[64] | flag2[64] | flagF[512]
    int*   flag1   = flags;
    int*   flag2   = flags + 64;
    int*   flagF   = flags + 128;
    int*   kk      = flags + 640;           // 8192
    int*   rankPart= kk + 8192;             // 32*8192
    int*   kPart   = rankPart + 262144;     // 32*8192
    float* Rpos    = (float*)(kPart + 262144);  // 524288
    float* Rneg    = Rpos + 524288;         // 524288
    float* Ppos    = Rneg + 524288;         // 524352 (8193 rows)
    float* Pneg    = Ppos + 524352;         // 524352
    float* h2      = Rpos;                  // alias: Rpos dead after kCDE

    kA_feat_wh<<<512, 256, 0, stream>>>(x, c1w, c1b, b1g, b1b, b1m, b1v,
                                        c2w, c2b, b2g, b2b, b2m, b2v,
                                        gW, gWb, ga1, ga2, Wh, s1, s2v);
    kB_rank<<<1024, 256, 0, stream>>>(s2v, s1, gab, rankPart, kPart, pmax, flags);
    kCDE<<<64, 256, 0, stream>>>(Wh, s2v, rankPart, kPart,
                                 Rpos, Rneg, spos, sneg, kk,
                                 csP, csN, csp, csn,
                                 Ppos, Pneg, ppos, pneg, flag1, flag2);
    kFG<<<512, 256, 0, stream>>>(s1, kk, pmax, gab, Ppos, Pneg, ppos, pneg,
                                 taW, tab, p1W, p1b, p2W, p2b, h2, out, flagF);
}

// Round 6
// 58.719 us; speedup vs baseline: 2.8345x; 2.8345x over previous
//
#include <hip/hip_runtime.h>
#include <hip/hip_bf16.h>

#define Hd 64
#define Sd 128
#define Bd 64
#define Nn 8192
#define EPSd 1e-5f

__device__ __forceinline__ float wred_sum(float v) {
    for (int m = 32; m; m >>= 1) v += __shfl_xor(v, m);
    return v;
}
__device__ __forceinline__ float wred_max(float v) {
    for (int m = 32; m; m >>= 1) v = fmaxf(v, __shfl_xor(v, m));
    return v;
}
// 64-lane inclusive scan
__device__ __forceinline__ float wscan_incl(float x, int lane) {
    #pragma unroll
    for (int d = 1; d < 64; d <<= 1) {
        float t = __shfl_up(x, d);
        if (lane >= d) x += t;
    }
    return x;
}

// A: conv1+bn1+relu -> conv2+bn2+relu -> (LDS) -> Wh, s1, s2  (32 nodes/block, 256 blocks)
__global__ __launch_bounds__(256) void kA_feat_wh(
        const float* __restrict__ x,
        const float* __restrict__ c1w, const float* __restrict__ c1b,
        const float* __restrict__ b1g, const float* __restrict__ b1b,
        const float* __restrict__ b1m, const float* __restrict__ b1v,
        const float* __restrict__ c2w, const float* __restrict__ c2b,
        const float* __restrict__ b2g, const float* __restrict__ b2b,
        const float* __restrict__ b2m, const float* __restrict__ b2v,
        const float* __restrict__ gW, const float* __restrict__ gWb,
        const float* __restrict__ a1, const float* __restrict__ a2,
        float* __restrict__ Wh, float* __restrict__ s1, float* __restrict__ s2) {
    __shared__ float buf[14464];           // phase1: h1[0..2176) | wtk[2176..14464)
    float* h1  = buf;                      // [col][cin], 34*64
    float* wtk = buf + 2176;               // [(k*16+cin4)*256 + c*4 + j]
    int b  = blockIdx.x >> 2;
    int s0 = (blockIdx.x & 3) * 32;
    int tid = threadIdx.x;
    // coalesced read of c2w, scattered LDS write
    for (int idx = tid; idx < 12288; idx += 256) {
        int c   = idx / 192;
        int rem = idx - c * 192;
        int cin = rem / 3;
        int k   = rem - cin * 3;
        int cin4 = cin >> 2, j = cin & 3;
        wtk[(k * 16 + cin4) * 256 + c * 4 + j] = c2w[idx];
    }
    for (int idx = tid; idx < 34 * 64; idx += 256) {
        int cin = idx & 63;
        int col = idx >> 6;
        int s   = s0 - 1 + col;
        float v = 0.f;
        if (s >= 0 && s < Sd) {
            float xm = (s > 0)      ? x[b * Sd + s - 1] : 0.f;
            float x0 = x[b * Sd + s];
            float xp = (s < Sd - 1) ? x[b * Sd + s + 1] : 0.f;
            float y  = c1w[cin * 3 + 0] * xm + c1w[cin * 3 + 1] * x0 + c1w[cin * 3 + 2] * xp + c1b[cin];
            float inv = b1g[cin] * rsqrtf(b1v[cin] + EPSd);
            v = fmaxf(y * inv + (b1b[cin] - b1m[cin] * inv), 0.f);
        }
        h1[col * 64 + cin] = v;
    }
    __syncthreads();
    int c = tid & 63, g = tid >> 6;
    float inv2 = b2g[c] * rsqrtf(b2v[c] + EPSd);
    float sh2  = b2b[c] - b2m[c] * inv2;
    float acc[8];
    #pragma unroll
    for (int p = 0; p < 8; ++p) acc[p] = c2b[c];
    {
        const float4* h14 = (const float4*)h1;
        const float4* wt4 = (const float4*)wtk;
        for (int cin4 = 0; cin4 < 16; ++cin4) {
            float4 xs[10];
            #pragma unroll
            for (int q = 0; q < 10; ++q) xs[q] = h14[(g * 8 + q) * 16 + cin4];
            #pragma unroll
            for (int k = 0; k < 3; ++k) {
                float4 w4 = wt4[(k * 16 + cin4) * 64 + c];
                #pragma unroll
                for (int p = 0; p < 8; ++p) {
                    float4 x4 = xs[p + k];
                    acc[p] += w4.x * x4.x + w4.y * x4.y + w4.z * x4.z + w4.w * x4.w;
                }
            }
        }
    }
    __syncthreads();   // conv reads done; safe to overwrite
    float*  xfl  = buf;                    // [sl][c], 32*64
    float4* gWT4 = (float4*)(buf + 2176);  // [kk4*64 + h]
    #pragma unroll
    for (int p = 0; p < 8; ++p)
        xfl[(g * 8 + p) * 64 + c] = fmaxf(acc[p] * inv2 + sh2, 0.f);
    for (int fidx = tid; fidx < 1024; fidx += 256) {
        int h_ = fidx >> 4, kk4 = fidx & 15;
        gWT4[kk4 * 64 + h_] = ((const float4*)gW)[fidx];
    }
    __syncthreads();
    int h = tid & 63, w = tid >> 6;
    float4 wreg[16];
    #pragma unroll
    for (int kk4 = 0; kk4 < 16; ++kk4) wreg[kk4] = gWT4[kk4 * 64 + h];
    float va1 = a1[h], va2 = a2[h], bias = gWb[h];
    const float4* xf4 = (const float4*)xfl;
    int n0 = b * Sd + s0;
    for (int q = 0; q < 8; ++q) {
        int sl = w * 8 + q;
        float accw = bias;
        #pragma unroll
        for (int kk4 = 0; kk4 < 16; ++kk4) {
            float4 x4 = xf4[sl * 16 + kk4];
            accw += wreg[kk4].x * x4.x + wreg[kk4].y * x4.y + wreg[kk4].z * x4.z + wreg[kk4].w * x4.w;
        }
        int n = n0 + sl;
        Wh[n * 64 + h] = accw;
        float r1 = wred_sum(accw * va1);
        float r2 = wred_sum(accw * va2);
        if (h == 0) { s1[n] = r1; s2[n] = r2; }
    }
}

// B: partial ranks AND partial k-counts (32 parts of 256 keys) + per-part max
__global__ __launch_bounds__(256) void kB_rank(
        const float* __restrict__ s2, const float* __restrict__ s1,
        const float* __restrict__ gab,
        int* __restrict__ rankPart, int* __restrict__ kPart,
        float* __restrict__ pmax) {
    __shared__ float4 ts4[64];
    int bid = blockIdx.x;
    int jg = bid >> 5, part = bid & 31;
    int tid = threadIdx.x;
    if (tid < 64) ts4[tid] = ((const float4*)(s2 + part * 256))[tid];
    __syncthreads();
    if (jg == 0 && tid < 64) {
        float4 t4 = ts4[tid];
        float m = fmaxf(fmaxf(t4.x, t4.y), fmaxf(t4.z, t4.w));
        m = wred_max(m);
        if (tid == 0) pmax[part] = m;
    }
    int j = jg * 256 + tid;
    float tj = s2[j];
    float negc = -(s1[j] + gab[0]);
    int jloc = j - part * 256;
    int cntR = 0, cntK = 0;
    #pragma unroll 4
    for (int q = 0; q < 64; ++q) {
        float4 t4 = ts4[q];
        int rb = q * 4;
        cntR += (t4.x < tj || (t4.x == tj && rb     < jloc)) ? 1 : 0;
        cntR += (t4.y < tj || (t4.y == tj && rb + 1 < jloc)) ? 1 : 0;
        cntR += (t4.z < tj || (t4.z == tj && rb + 2 < jloc)) ? 1 : 0;
        cntR += (t4.w < tj || (t4.w == tj && rb + 3 < jloc)) ? 1 : 0;
        cntK += (t4.x <= negc) ? 1 : 0;
        cntK += (t4.y <= negc) ? 1 : 0;
        cntK += (t4.z <= negc) ? 1 : 0;
        cntK += (t4.w <= negc) ? 1 : 0;
    }
    rankPart[part * 8192 + j] = cntR;
    kPart[part * 8192 + j]    = cntK;
}

// C: sum partials -> jsorted (index scatter), e^t / e^{0.2t} in sorted order, kk
__global__ __launch_bounds__(256) void kC_scatter(
        const float* __restrict__ s2,
        const int* __restrict__ rankPart, const int* __restrict__ kPart,
        int* __restrict__ jsorted, float* __restrict__ e1so, float* __restrict__ e2so,
        int* __restrict__ kk) {
    int j = blockIdx.x * 256 + threadIdx.x;
    int r = 0, kq = 0;
    #pragma unroll
    for (int p = 0; p < 32; ++p) { r += rankPart[p * 8192 + j]; kq += kPart[p * 8192 + j]; }
    float t = s2[j];
    jsorted[r] = j;
    e1so[r] = expf(t);
    e2so[r] = expf(0.2f * t);
    kk[j] = kq;
}

// D: dual-role, 128 blocks. bid<64: chunk sums. bid>=64: chunk-local prefixes (no base).
__global__ __launch_bounds__(256) void kD_dual(
        const float* __restrict__ Wh, const int* __restrict__ jsorted,
        const float* __restrict__ e1so, const float* __restrict__ e2so,
        float* __restrict__ csP, float* __restrict__ csN,
        float* __restrict__ csp, float* __restrict__ csn,
        float* __restrict__ PLpos, float* __restrict__ PLneg,
        float* __restrict__ pLp, float* __restrict__ pLn) {
    __shared__ float ldsA[4][64], ldsB[4][64];
    int bid = blockIdx.x, tid = threadIdx.x;
    int h = tid & 63, w = tid >> 6;
    if (bid < 64) {
        int ch = bid;
        int rb = ch * 128 + w * 32;
        double aP = 0.0, aN = 0.0;
        #pragma unroll
        for (int r = 0; r < 32; ++r) {
            int j = jsorted[rb + r];
            float wv = Wh[j * 64 + h];
            aP += e1so[rb + r] * wv;
            aN += e2so[rb + r] * wv;
        }
        ldsA[w][h] = (float)aP; ldsB[w][h] = (float)aN;
        __syncthreads();
        if (w == 0) {
            csP[ch * 64 + h] = ldsA[0][h] + ldsA[1][h] + ldsA[2][h] + ldsA[3][h];
        } else if (w == 1) {
            csN[ch * 64 + h] = ldsB[0][h] + ldsB[1][h] + ldsB[2][h] + ldsB[3][h];
        } else if (w == 2) {
            float vv = e1so[ch * 128 + h] + e1so[ch * 128 + 64 + h];
            vv = wred_sum(vv);
            if (h == 0) csp[ch] = vv;
        } else {
            float vv = e2so[ch * 128 + h] + e2so[ch * 128 + 64 + h];
            vv = wred_sum(vv);
            if (h == 0) csn[ch] = vv;
        }
    } else {
        int ch = bid - 64;
        int rb = ch * 128 + w * 32;
        float v[32], u[32];
        #pragma unroll
        for (int r = 0; r < 32; ++r) {
            int j = jsorted[rb + r];
            float wv = Wh[j * 64 + h];
            v[r] = e1so[rb + r] * wv;
            u[r] = e2so[rb + r] * wv;
        }
        double sP = 0.0, sN = 0.0;
        #pragma unroll
        for (int r = 0; r < 32; ++r) { sP += v[r]; sN += u[r]; }
        ldsA[w][h] = (float)sP; ldsB[w][h] = (float)sN;
        __syncthreads();
        float offP = 0.f, offN = 0.f;
        #pragma unroll
        for (int w2 = 0; w2 < 4; ++w2) if (w2 < w) { offP += ldsA[w2][h]; offN += ldsB[w2][h]; }
        double a = 0.0;
        #pragma unroll
        for (int r = 0; r < 32; ++r) { PLpos[(rb + r) * 64 + h] = offP + (float)a; a += v[r]; }
        a = 0.0;
        #pragma unroll
        for (int r = 0; r < 32; ++r) { PLneg[(rb + r) * 64 + h] = offN + (float)a; a += u[r]; }
        // chunk-local scalar prefixes (no base)
        if (w == 0) {
            int lane = h;
            float v0 = e1so[ch * 128 + lane], v1 = e1so[ch * 128 + 64 + lane];
            float i0 = wscan_incl(v0, lane);
            float t0 = __shfl(i0, 63);
            float i1 = wscan_incl(v1, lane);
            pLp[ch * 128 + lane]      = i0 - v0;
            pLp[ch * 128 + 64 + lane] = t0 + i1 - v1;
        } else if (w == 1) {
            int lane = h;
            float v0 = e2so[ch * 128 + lane], v1 = e2so[ch * 128 + 64 + lane];
            float i0 = wscan_incl(v0, lane);
            float t0 = __shfl(i0, 63);
            float i1 = wscan_incl(v1, lane);
            pLn[ch * 128 + lane]      = i0 - v0;
            pLn[ch * 128 + 64 + lane] = t0 + i1 - v1;
        }
    }
}

// F: per-node hp (chunk-base built in LDS) + time-attn -> h2
__global__ __launch_bounds__(256) void kF_node(
        const float* __restrict__ s1, const int* __restrict__ kk,
        const float* __restrict__ pmax, const float* __restrict__ gab,
        const float* __restrict__ PLpos, const float* __restrict__ PLneg,
        const float* __restrict__ pLp, const float* __restrict__ pLn,
        const float* __restrict__ csP, const float* __restrict__ csN,
        const float* __restrict__ csp, const float* __restrict__ csn,
        const float* __restrict__ taW, const float* __restrict__ tab,
        float* __restrict__ h2) {
    __shared__ float4 wt4[1024];     // taW: [kk4*64 + h]
    __shared__ float hl[16 * 64];
    __shared__ float cpP[65 * 64], cpN[65 * 64];   // exclusive chunk-base prefixes
    __shared__ float cpp[65], cpn[65];
    int tid = threadIdx.x;
    int h = tid & 63, w = tid >> 6;
    for (int fidx = tid; fidx < 1024; fidx += 256) {
        int h_ = fidx >> 4, kk4 = fidx & 15;
        wt4[kk4 * 64 + h_] = ((const float4*)taW)[fidx];
    }
    if (w == 0) {
        double a = 0.0;
        for (int ch = 0; ch < 64; ++ch) { cpP[ch * 64 + h] = (float)a; a += csP[ch * 64 + h]; }
        cpP[64 * 64 + h] = (float)a;
    } else if (w == 1) {
        double a = 0.0;
        for (int ch = 0; ch < 64; ++ch) { cpN[ch * 64 + h] = (float)a; a += csN[ch * 64 + h]; }
        cpN[64 * 64 + h] = (float)a;
    } else if (w == 2) {
        float v = csp[h];
        float i = wscan_incl(v, h);
        cpp[h] = i - v;
        if (h == 63) cpp[64] = i;
    } else {
        float v = csn[h];
        float i = wscan_incl(v, h);
        cpn[h] = i - v;
        if (h == 63) cpn[64] = i;
    }
    float tmx = pmax[tid & 31];
    tmx = wred_max(tmx);
    __syncthreads();
    float gabv = gab[0];
    float tabv = tab[h];
    float Tp  = cpP[64 * 64 + h];
    float ppT = cpp[64];
    for (int r = 0; r < 4; ++r) {
        int n = blockIdx.x * 16 + w * 4 + r;
        float c = s1[n] + gabv;
        int k = kk[n];
        int ch = k >> 7;
        float PLpv = 0.f, PLnv = 0.f, pLpv = 0.f, pLnv = 0.f;
        if (k < Nn) {
            PLpv = PLpos[k * 64 + h]; PLnv = PLneg[k * 64 + h];
            pLpv = pLp[k];            pLnv = pLn[k];
        }
        float Pp = cpP[ch * 64 + h] + PLpv;
        float Pn = cpN[ch * 64 + h] + PLnv;
        float qp = cpp[ch] + pLpv;
        float qn = cpn[ch] + pLnv;
        float z = c + tmx;
        float m = (z >= 0.f) ? z : 0.2f * z;
        float E1 = expf(c - m), E2 = expf(0.2f * c - m);
        float num = E1 * (Tp - Pp) + E2 * Pn;
        float den = E1 * (ppT - qp) + E2 * qn;
        float hp = num / den;
        int slot = w * 4 + r;
        hl[slot * 64 + h] = hp;
        float vv = tabv;
        const float4* hlr = (const float4*)&hl[slot * 64];
        #pragma unroll
        for (int kk4 = 0; kk4 < 16; ++kk4) {
            float4 w4 = wt4[kk4 * 64 + h];
            float4 x4 = hlr[kk4];
            vv += w4.x * x4.x + w4.y * x4.y + w4.z * x4.z + w4.w * x4.w;
        }
        float mx = wred_max(vv);
        float e = expf(vv - mx);
        float se = wred_sum(e);
        h2[n * 64 + h] = hp * (e / se);
    }
}

// G: mean over S + MLP head -> out
__global__ __launch_bounds__(256) void kG_pool(
        const float* __restrict__ h2,
        const float* __restrict__ p1W, const float* __restrict__ p1b,
        const float* __restrict__ p2W, const float* __restrict__ p2b,
        float* __restrict__ out) {
    __shared__ float pacc[4 * 64];
    __shared__ float pl[64];
    __shared__ float p1s[32 * 65];
    int tid = threadIdx.x, b = blockIdx.x;
    int w = tid >> 6, h = tid & 63;
    for (int idx = tid; idx < 2048; idx += 256) {
        int q = idx >> 6, kq = idx & 63;
        p1s[q * 65 + kq] = p1W[idx];
    }
    float a = 0.f;
    for (int s = w * 32; s < w * 32 + 32; ++s) a += h2[(b * Sd + s) * 64 + h];
    pacc[w * 64 + h] = a;
    __syncthreads();
    if (w == 0) {
        float pooled = (pacc[h] + pacc[64 + h] + pacc[128 + h] + pacc[192 + h]) * (1.f / 128.f);
        pl[h] = pooled;
        float val = 0.f;
        if (h < 32) {
            float acc = p1b[h];
            #pragma unroll
            for (int kq = 0; kq < 64; ++kq) acc += p1s[h * 65 + kq] * pl[kq];
            val = p2W[h] * fmaxf(acc, 0.f);
        }
        val = wred_sum(val);
        if (h == 0) out[b] = val + p2b[0];
    }
}

extern "C" void kernel_launch(void* const* d_in, const int* in_sizes, int n_in,
                              void* d_out, int out_size, void* d_ws, size_t ws_size,
                              hipStream_t stream) {
    const float* x    = (const float*)d_in[0];
    const float* c1w  = (const float*)d_in[1];
    const float* c1b  = (const float*)d_in[2];
    const float* b1g  = (const float*)d_in[3];
    const float* b1b  = (const float*)d_in[4];
    const float* b1m  = (const float*)d_in[5];
    const float* b1v  = (const float*)d_in[6];
    const float* c2w  = (const float*)d_in[7];
    const float* c2b  = (const float*)d_in[8];
    const float* b2g  = (const float*)d_in[9];
    const float* b2b  = (const float*)d_in[10];
    const float* b2m  = (const float*)d_in[11];
    const float* b2v  = (const float*)d_in[12];
    const float* gW   = (const float*)d_in[13];
    const float* gWb  = (const float*)d_in[14];
    const float* ga1  = (const float*)d_in[15];
    const float* ga2  = (const float*)d_in[16];
    const float* gab  = (const float*)d_in[17];
    const float* taW  = (const float*)d_in[18];
    const float* tab  = (const float*)d_in[19];
    const float* p1W  = (const float*)d_in[20];
    const float* p1b  = (const float*)d_in[21];
    const float* p2W  = (const float*)d_in[22];
    const float* p2b  = (const float*)d_in[23];
    float* out = (float*)d_out;

    float* ws = (float*)d_ws;
    float* Wh      = ws;                    // 524288
    float* s1      = Wh + 524288;           // 8192
    float* s2v     = s1 + 8192;             // 8192
    float* e1so    = s2v + 8192;            // 8192
    float* e2so    = e1so + 8192;           // 8192
    float* csP     = e2so + 8192;           // 4096
    float* csN     = csP + 4096;            // 4096
    float* csp     = csN + 4096;            // 64
    float* csn     = csp + 64;              // 64
    float* pmax    = csn + 64;              // 64 (32 used)
    float* pLp     = pmax + 64;             // 8192
    float* pLn     = pLp + 8192;            // 8192
    float* PLpos   = pLn + 8192;            // 524288
    float* PLneg   = PLpos + 524288;        // 524288
    int*   jsorted = (int*)(PLneg + 524288);// 8192
    int*   kk      = jsorted + 8192;        // 8192
    int*   rankPart= kk + 8192;             // 262144
    int*   kPart   = rankPart + 262144;     // 262144
    float* h2      = (float*)rankPart;      // alias: rankPart/kPart dead after kC

    kA_feat_wh<<<256, 256, 0, stream>>>(x, c1w, c1b, b1g, b1b, b1m, b1v,
                                        c2w, c2b, b2g, b2b, b2m, b2v,
                                        gW, gWb, ga1, ga2, Wh, s1, s2v);
    kB_rank<<<1024, 256, 0, stream>>>(s2v, s1, gab, rankPart, kPart, pmax);
    kC_scatter<<<32, 256, 0, stream>>>(s2v, rankPart, kPart, jsorted, e1so, e2so, kk);
    kD_dual<<<128, 256, 0, stream>>>(Wh, jsorted, e1so, e2so, csP, csN, csp, csn,
                                     PLpos, PLneg, pLp, pLn);
    kF_node<<<512, 256, 0, stream>>>(s1, kk, pmax, gab, PLpos, PLneg, pLp, pLn,
                                     csP, csN, csp, csn, taW, tab, h2);
    kG_pool<<<64, 256, 0, stream>>>(h2, p1W, p1b, p2W, p2b, out);
}